// Round 14
// baseline (387.661 us; speedup 1.0000x reference)
//
#include <hip/hip_runtime.h>
#include <hip/hip_bf16.h>
#include <cstdint>
#include <cstddef>

// ---------------------------------------------------------------------------
// Attention block on MI355X (gfx950), bf16 MFMA everywhere.
//   x = LN(seq); q,k,v = x@W{q,k,v}.T + b (q pre-scaled by 0.125*log2e)
//   s' = q.k (log2 domain); e = 2^s'; w = e^2/(e+e^mu) = rcp(t + emu*t^2),
//   t = 2^-s'.  P = w / rowsum(w); out = (P @ v, heads merged) @ Wo.T + bo
// Attn: LDS-FREE. K/V per (b,h) = 512 KB -> L2-resident (XCD-swizzled so each
// XCD's 8 heads = 4 MB = its L2). Waves read K/V fragments directly from
// global; the 4 ch-loads are cacheline-complete. No barriers, no LDS, no
// bank conflicts; 128-thr blocks = 2 independent waves. In-register P.
// ---------------------------------------------------------------------------

typedef __bf16 bf16_t;
typedef __bf16 bf16x4 __attribute__((ext_vector_type(4)));
typedef __bf16 bf16x8 __attribute__((ext_vector_type(8)));
typedef float  f32x4  __attribute__((ext_vector_type(4)));
typedef float  f32x16 __attribute__((ext_vector_type(16)));
typedef unsigned u32x4 __attribute__((ext_vector_type(4)));

#define MFMA16(a, b, c) __builtin_amdgcn_mfma_f32_16x16x32_bf16((a), (b), (c), 0, 0, 0)
#define MFMA32(a, b, c) __builtin_amdgcn_mfma_f32_32x32x16_bf16((a), (b), (c), 0, 0, 0)

#if __has_builtin(__builtin_amdgcn_exp2f)
#define VEXP2(x) __builtin_amdgcn_exp2f(x)
#else
#define VEXP2(x) __expf((x) * 0.6931471805599453f)
#endif

// packed f32->bf16 (RTNE), dst.lo16=cvt(a), dst.hi16=cvt(b)  [r5-proven]
__device__ __forceinline__ unsigned cvtpk_bf16(float a, float b) {
  unsigned r;
  asm("v_cvt_pk_bf16_f32 %0, %1, %2" : "=v"(r) : "v"(a), "v"(b));
  return r;
}

// full cross-half swap between two registers (gfx950)  [r5-proven, volatile]
__device__ __forceinline__ void plane32_swap(unsigned& a, unsigned& b) {
  asm volatile("v_permlane32_swap_b32 %0, %1" : "+v"(a), "+v"(b));
}

__device__ __forceinline__ void gload16(void* lds, const void* g) {
  __builtin_amdgcn_global_load_lds(
      (__attribute__((address_space(1))) void*)(uintptr_t)g,
      (__attribute__((address_space(3))) void*)(uint32_t)(uintptr_t)lds,
      16, 0, 0);
}

// ---------------- fused prep: weights fp32->bf16  +  LayerNorm -------------
__global__ __launch_bounds__(256) void prep_k(
    const float* __restrict__ s0, const float* __restrict__ s1,
    const float* __restrict__ s2, const float* __restrict__ s3,
    bf16_t* __restrict__ wdst,
    const float* __restrict__ x, const float* __restrict__ gamma,
    const float* __restrict__ beta, bf16_t* __restrict__ xout)
{
  int bid = blockIdx.x;
  int tid = threadIdx.x;
  if (bid < 4096) {
    int part = bid >> 10;
    const float* src = part == 0 ? s0 : part == 1 ? s1 : part == 2 ? s2 : s3;
    int i = (bid & 1023) * 256 + tid;
    float4 v = ((const float4*)src)[i];
    bf16x4 o = { (bf16_t)v.x, (bf16_t)v.y, (bf16_t)v.z, (bf16_t)v.w };
    *(bf16x4*)(wdst + (((size_t)part) << 20) + (size_t)i * 4) = o;
  } else {
    int row = bid - 4096;
    float4 v = ((const float4*)(x + (size_t)row * 1024))[tid];
    float s  = v.x + v.y + v.z + v.w;
    float ss = v.x * v.x + v.y * v.y + v.z * v.z + v.w * v.w;
#pragma unroll
    for (int m = 1; m < 64; m <<= 1) { s += __shfl_xor(s, m); ss += __shfl_xor(ss, m); }
    __shared__ float sh_s[4], sh_q[4];
    int w = tid >> 6;
    if ((tid & 63) == 0) { sh_s[w] = s; sh_q[w] = ss; }
    __syncthreads();
    s  = sh_s[0] + sh_s[1] + sh_s[2] + sh_s[3];
    ss = sh_q[0] + sh_q[1] + sh_q[2] + sh_q[3];
    float mean = s * (1.0f / 1024.0f);
    float var  = ss * (1.0f / 1024.0f) - mean * mean;
    float rstd = rsqrtf(var + 1e-6f);
    float4 gv = ((const float4*)gamma)[tid];
    float4 bv = ((const float4*)beta)[tid];
    bf16x4 o = { (bf16_t)((v.x - mean) * rstd * gv.x + bv.x),
                 (bf16_t)((v.y - mean) * rstd * gv.y + bv.y),
                 (bf16_t)((v.z - mean) * rstd * gv.z + bv.z),
                 (bf16_t)((v.w - mean) * rstd * gv.w + bv.w) };
    *(bf16x4*)(xout + (size_t)row * 1024 + tid * 4) = o;
  }
}

// ---------------- NT GEMM: C[M,N] = A[M,K] * Bw[N,K]^T + bias --------------
__global__ __launch_bounds__(256) void gemm_bt(
    const bf16_t* __restrict__ A, const bf16_t* __restrict__ Bw,
    const float* __restrict__ b0, const float* __restrict__ b1,
    const float* __restrict__ b2,
    void* __restrict__ o0, void* __restrict__ o1, void* __restrict__ o2,
    int M, int N, int K, int fused)
{
  __shared__ __align__(16) bf16_t a_lds[2][128][32];
  __shared__ __align__(16) bf16_t b_lds[2][128][32];
  const int tid = threadIdx.x;
  const int l = tid & 63, w = tid >> 6;
  const int wr = w >> 1, wc = w & 1;
  const int m0 = blockIdx.y * 128, n0 = blockIdx.x * 128;
  const int lr = l & 15, lg = l >> 4;

  f32x4 acc[4][4] = {};

  const int srow = tid >> 2;
  const int scol = (tid & 3) * 8;
  const bf16_t* ag = A  + (size_t)(m0 + srow) * K + scol;
  const bf16_t* bg = Bw + (size_t)(n0 + srow) * K + scol;

  gload16((char*)a_lds[0] + tid * 16,        ag);
  gload16((char*)a_lds[0] + 4096 + tid * 16, ag + (size_t)64 * K);
  gload16((char*)b_lds[0] + tid * 16,        bg);
  gload16((char*)b_lds[0] + 4096 + tid * 16, bg + (size_t)64 * K);
  __syncthreads();

  int cur = 0;
  for (int k0 = 0; k0 < K; k0 += 32) {
    if (k0 + 32 < K) {
      gload16((char*)a_lds[cur ^ 1] + tid * 16,        ag + k0 + 32);
      gload16((char*)a_lds[cur ^ 1] + 4096 + tid * 16, ag + (size_t)64 * K + k0 + 32);
      gload16((char*)b_lds[cur ^ 1] + tid * 16,        bg + k0 + 32);
      gload16((char*)b_lds[cur ^ 1] + 4096 + tid * 16, bg + (size_t)64 * K + k0 + 32);
    }
    bf16x8 af[4], bf[4];
#pragma unroll
    for (int i = 0; i < 4; ++i) {
      af[i] = *(const bf16x8*)&a_lds[cur][wr * 64 + i * 16 + lr][lg * 8];
      bf[i] = *(const bf16x8*)&b_lds[cur][wc * 64 + i * 16 + lr][lg * 8];
    }
#pragma unroll
    for (int i = 0; i < 4; ++i)
#pragma unroll
      for (int j = 0; j < 4; ++j)
        acc[i][j] = MFMA16(af[i], bf[j], acc[i][j]);
    __syncthreads();
    cur ^= 1;
  }

  int matsel = fused ? (n0 >> 10) : 0;
  const float* bias = matsel == 0 ? b0 : matsel == 1 ? b1 : b2;
  float bs[4];
#pragma unroll
  for (int j = 0; j < 4; ++j) bs[j] = bias[(n0 + wc * 64 + j * 16 + lr) & 1023];

#pragma unroll
  for (int i = 0; i < 4; ++i) {
#pragma unroll
    for (int j = 0; j < 4; ++j) {
      if (fused && matsel == 2) {
        // V^T scatter: rows r are consecutive s -> one packed bf16x4 store
        int row0 = m0 + wr * 64 + i * 16 + lg * 4;
        int col  = n0 + wc * 64 + j * 16 + lr;
        int nn = col & 1023;
        int bb = row0 >> 11, s0 = row0 & 2047, hh = nn >> 6, d = nn & 63;
        bf16x4 pv;
#pragma unroll
        for (int r = 0; r < 4; ++r) pv[r] = (bf16_t)(acc[i][j][r] + bs[j]);
        *(bf16x4*)((bf16_t*)o2 + ((((size_t)bb * 16 + hh) * 64) + d) * 2048 + s0) = pv;
      } else {
#pragma unroll
        for (int r = 0; r < 4; ++r) {
          int row = m0 + wr * 64 + i * 16 + lg * 4 + r;
          int col = n0 + wc * 64 + j * 16 + lr;
          float v = acc[i][j][r] + bs[j];
          if (!fused) {
            ((float*)o0)[(size_t)row * N + col] = v;
          } else {
            int nn = col & 1023;
            int bb = row >> 11, s = row & 2047, hh = nn >> 6, d = nn & 63;
            bf16_t* o = matsel ? (bf16_t*)o1 : (bf16_t*)o0;
            // fold 1/sqrt(hd) * log2(e) into q -> scores arrive in log2 domain
            if (matsel == 0) v *= 0.18033688011112042f;
            o[((((size_t)bb * 16 + hh) * 2048 + s) << 6) + d] = (bf16_t)v;
          }
        }
      }
    }
  }
}

// ---------------- fused attention (LDS-free, 32x32 MFMA, in-reg P) ---------
// grid 2048 (XCD-swizzled: 8 bh per XCD -> K/V 4 MB = L2), 128 thr = 2
// independent waves x 32 q-rows. K/V fragments read directly from global
// (L2-hot); the 4 ch-loads per row-group fully consume each 128B cacheline.
// No LDS, no barriers. Swapped QK^T on 32x32x16; in-register P.
__global__ __launch_bounds__(128) void attn_k(
    const bf16_t* __restrict__ q, const bf16_t* __restrict__ k,
    const bf16_t* __restrict__ vT, const float* __restrict__ mu_p,
    bf16_t* __restrict__ out)
{
  const int S = 2048;
  int hw = blockIdx.x;
  int vid = (hw & 7) * 256 + (hw >> 3);   // 8 XCD chunks of 256; 32 blocks/bh
  int qt = vid & 31;                      // q-tile of 64 rows
  int bh = vid >> 5;
  int h = bh & 15, b = bh >> 4;

  const bf16_t* qb = q + ((size_t)bh * S + qt * 64) * 64;
  const char* kb = (const char*)(k  + (size_t)bh * S * 64);   // [s][64] 128B rows
  const char* vb = (const char*)(vT + (size_t)bh * 64 * S);   // [d][2048] 4KB rows
  const float emu = __expf(mu_p[0]);      // e^mu (natural)

  const int tid = threadIdx.x, l = tid & 63, w = tid >> 6;    // w in 0..1
  const int l31 = l & 31, hi = l >> 5;

  // Q fragments: lane holds Q[q=w*32+l31][hd=16ch+8hi+j]
  bf16x8 qf[4];
#pragma unroll
  for (int ch = 0; ch < 4; ++ch)
    qf[ch] = *(const bf16x8*)(qb + (size_t)(w * 32 + l31) * 64 + ch * 16 + hi * 8);

  f32x16 oAcc[2] = {};                    // [dfrag]
  float rs0 = 0.f, rs1 = 0.f;

  for (int t = 0; t < 32; ++t) {
#pragma unroll
    for (int kh = 0; kh < 2; ++kh) {       // key half: k-local = kh*32 + ...
      // K fragments direct from global: row s = t*64 + kh*32 + l31.
      // The 4 ch-loads together consume each 128B K-row line completely.
      const char* krow = kb + (size_t)(t * 64 + kh * 32 + l31) * 128 + hi * 16;
      bf16x8 kf0 = *(const bf16x8*)(krow);
      bf16x8 kf1 = *(const bf16x8*)(krow + 32);
      bf16x8 kf2 = *(const bf16x8*)(krow + 64);
      bf16x8 kf3 = *(const bf16x8*)(krow + 96);
      f32x16 sc = {};
      __builtin_amdgcn_s_setprio(1);
      sc = MFMA32(kf0, qf[0], sc);
      sc = MFMA32(kf1, qf[1], sc);
      sc = MFMA32(kf2, qf[2], sc);
      sc = MFMA32(kf3, qf[3], sc);
      __builtin_amdgcn_s_setprio(0);

      // w = rcp(d), d = t + emu*t^2, t = 2^-s'.  Montgomery pair-inverse:
      // one v_rcp per TWO scores (inv=rcp(d0*d1); w0=inv*d1; w1=inv*d0).
      unsigned U[8];
#pragma unroll
      for (int m = 0; m < 8; ++m) {
        float t0 = VEXP2(-sc[2 * m]);
        float t1 = VEXP2(-sc[2 * m + 1]);
        float d0 = fmaf(emu * t0, t0, t0);
        float d1 = fmaf(emu * t1, t1, t1);
        float inv = __builtin_amdgcn_rcpf(d0 * d1);
        float w0 = inv * d1;
        float w1 = inv * d0;
        rs0 += w0; rs1 += w1;
        U[m] = cvtpk_bf16(w0, w1);
      }
      // cross-half exchange -> PV A-fragments
      plane32_swap(U[0], U[2]);
      plane32_swap(U[1], U[3]);
      plane32_swap(U[4], U[6]);
      plane32_swap(U[5], U[7]);
      // PV: chunk cc covers k-local = kh*32 + cc*16 + 8hi + j  ->
      // global s = t*64 + (kh*2+cc)*16 + hi*8
      __builtin_amdgcn_s_setprio(1);
#pragma unroll
      for (int cc = 0; cc < 2; ++cc) {
        u32x4 uu = { U[cc * 4 + 0], U[cc * 4 + 1], U[cc * 4 + 2], U[cc * 4 + 3] };
        bf16x8 pa = __builtin_bit_cast(bf16x8, uu);
        int soff = (t * 64 + (kh * 2 + cc) * 16 + hi * 8) * 2;   // bytes
#pragma unroll
        for (int df = 0; df < 2; ++df) {
          bf16x8 vf = *(const bf16x8*)(vb + (size_t)(df * 32 + l31) * 4096 + soff);
          oAcc[df] = MFMA32(pa, vf, oAcc[df]);
        }
      }
      __builtin_amdgcn_s_setprio(0);
    }
  }

  // row sums: lane holds partial for q = l31; lanes l and l+32 complete the row
  float rs = rs0 + rs1;
  rs += __shfl_xor(rs, 32);
  float rinv = __builtin_amdgcn_rcpf(rs);

#pragma unroll
  for (int r = 0; r < 16; ++r) {
    int q_loc = (r & 3) + 8 * (r >> 2) + 4 * hi;
    float ro = __shfl(rinv, q_loc);
    size_t row = (size_t)b * 2048 + qt * 64 + w * 32 + q_loc;
#pragma unroll
    for (int df = 0; df < 2; ++df) {
      out[row * 1024 + h * 64 + df * 32 + l31] = (bf16_t)(oAcc[df][r] * ro);
    }
  }
}

// ---------------------------------------------------------------------------
extern "C" void kernel_launch(void* const* d_in, const int* in_sizes, int n_in,
                              void* d_out, int out_size, void* d_ws, size_t ws_size,
                              hipStream_t stream) {
  const float* seq = (const float*)d_in[0];
  const float* g   = (const float*)d_in[1];
  const float* be  = (const float*)d_in[2];
  const float* Wq  = (const float*)d_in[3];
  const float* bq  = (const float*)d_in[4];
  const float* Wk  = (const float*)d_in[5];
  const float* bk  = (const float*)d_in[6];
  const float* Wv  = (const float*)d_in[7];
  const float* bv  = (const float*)d_in[8];
  const float* Wo  = (const float*)d_in[9];
  const float* bo  = (const float*)d_in[10];
  const float* mu  = (const float*)d_in[11];

  char* ws = (char*)d_ws;
  bf16_t* xb   = (bf16_t*)ws;  ws += (size_t)8192 * 1024 * 2;
  bf16_t* wAll = (bf16_t*)ws;  ws += (size_t)4 * 1024 * 1024 * 2;
  bf16_t* qb   = (bf16_t*)ws;  ws += (size_t)8192 * 1024 * 2;
  bf16_t* kbuf = (bf16_t*)ws;  ws += (size_t)8192 * 1024 * 2;
  bf16_t* vtb  = (bf16_t*)ws;  ws += (size_t)8192 * 1024 * 2;
  bf16_t* ab   = (bf16_t*)ws;  ws += (size_t)8192 * 1024 * 2;
  bf16_t* wqkv = wAll;
  bf16_t* wob  = wAll + (size_t)3 * 1024 * 1024;

  dim3 blk(256);
  prep_k<<<dim3(12288), blk, 0, stream>>>(Wq, Wk, Wv, Wo, wAll, seq, g, be, xb);
  gemm_bt<<<dim3(24, 64), blk, 0, stream>>>(xb, wqkv, bq, bk, bv,
                                            qb, kbuf, vtb, 8192, 3072, 1024, 1);
  attn_k<<<dim3(2048), dim3(128), 0, stream>>>(qb, kbuf, vtb, mu, ab);
  gemm_bt<<<dim3(8, 64), blk, 0, stream>>>(ab, wob, bo, nullptr, nullptr,
                                           d_out, nullptr, nullptr, 8192, 1024, 1024, 0);
}

// Round 15
// 207.270 us; speedup vs baseline: 1.8703x; 1.8703x over previous
//
#include <hip/hip_runtime.h>
#include <hip/hip_bf16.h>
#include <cstdint>
#include <cstddef>

// ---------------------------------------------------------------------------
// Attention block on MI355X (gfx950), bf16 MFMA everywhere.
//   x = LN(seq); q,k,v = x@W{q,k,v}.T + b (q pre-scaled by 0.125*log2e)
//   s' = q.k (log2 domain); e = 2^s'; w = e^2/(e+e^mu) = rcp(t + emu*t^2),
//   t = 2^-s'.  P = w / rowsum(w); out = (P @ v, heads merged) @ Wo.T + bo
// Attn: r13 structure + counted-vmcnt deep pipeline: 4-deep LDS ring,
// prefetch 2 tiles ahead, raw s_barrier with vmcnt(4) (never 0 in the main
// loop) instead of __syncthreads' full drain. Per-wave 2 VMEM calls/tile ->
// vmcnt(4) == "tiles t+1,t+2 may be in flight; tile t landed". Ring distance
// proof: writes {t+1,t+2} vs reads {t-1,t}: distances 1..3 mod 4 != 0.
// ---------------------------------------------------------------------------

typedef __bf16 bf16_t;
typedef __bf16 bf16x4 __attribute__((ext_vector_type(4)));
typedef __bf16 bf16x8 __attribute__((ext_vector_type(8)));
typedef float  f32x4  __attribute__((ext_vector_type(4)));
typedef float  f32x16 __attribute__((ext_vector_type(16)));
typedef unsigned u32x4 __attribute__((ext_vector_type(4)));

#define MFMA16(a, b, c) __builtin_amdgcn_mfma_f32_16x16x32_bf16((a), (b), (c), 0, 0, 0)
#define MFMA32(a, b, c) __builtin_amdgcn_mfma_f32_32x32x16_bf16((a), (b), (c), 0, 0, 0)

#if __has_builtin(__builtin_amdgcn_exp2f)
#define VEXP2(x) __builtin_amdgcn_exp2f(x)
#else
#define VEXP2(x) __expf((x) * 0.6931471805599453f)
#endif

// packed f32->bf16 (RTNE), dst.lo16=cvt(a), dst.hi16=cvt(b)  [r5-proven]
__device__ __forceinline__ unsigned cvtpk_bf16(float a, float b) {
  unsigned r;
  asm("v_cvt_pk_bf16_f32 %0, %1, %2" : "=v"(r) : "v"(a), "v"(b));
  return r;
}

// full cross-half swap between two registers (gfx950)  [r5-proven, volatile]
__device__ __forceinline__ void plane32_swap(unsigned& a, unsigned& b) {
  asm volatile("v_permlane32_swap_b32 %0, %1" : "+v"(a), "+v"(b));
}

__device__ __forceinline__ void gload16(void* lds, const void* g) {
  __builtin_amdgcn_global_load_lds(
      (__attribute__((address_space(1))) void*)(uintptr_t)g,
      (__attribute__((address_space(3))) void*)(uint32_t)(uintptr_t)lds,
      16, 0, 0);
}

// ---------------- fused prep: weights fp32->bf16  +  LayerNorm -------------
__global__ __launch_bounds__(256) void prep_k(
    const float* __restrict__ s0, const float* __restrict__ s1,
    const float* __restrict__ s2, const float* __restrict__ s3,
    bf16_t* __restrict__ wdst,
    const float* __restrict__ x, const float* __restrict__ gamma,
    const float* __restrict__ beta, bf16_t* __restrict__ xout)
{
  int bid = blockIdx.x;
  int tid = threadIdx.x;
  if (bid < 4096) {
    int part = bid >> 10;
    const float* src = part == 0 ? s0 : part == 1 ? s1 : part == 2 ? s2 : s3;
    int i = (bid & 1023) * 256 + tid;
    float4 v = ((const float4*)src)[i];
    bf16x4 o = { (bf16_t)v.x, (bf16_t)v.y, (bf16_t)v.z, (bf16_t)v.w };
    *(bf16x4*)(wdst + (((size_t)part) << 20) + (size_t)i * 4) = o;
  } else {
    int row = bid - 4096;
    float4 v = ((const float4*)(x + (size_t)row * 1024))[tid];
    float s  = v.x + v.y + v.z + v.w;
    float ss = v.x * v.x + v.y * v.y + v.z * v.z + v.w * v.w;
#pragma unroll
    for (int m = 1; m < 64; m <<= 1) { s += __shfl_xor(s, m); ss += __shfl_xor(ss, m); }
    __shared__ float sh_s[4], sh_q[4];
    int w = tid >> 6;
    if ((tid & 63) == 0) { sh_s[w] = s; sh_q[w] = ss; }
    __syncthreads();
    s  = sh_s[0] + sh_s[1] + sh_s[2] + sh_s[3];
    ss = sh_q[0] + sh_q[1] + sh_q[2] + sh_q[3];
    float mean = s * (1.0f / 1024.0f);
    float var  = ss * (1.0f / 1024.0f) - mean * mean;
    float rstd = rsqrtf(var + 1e-6f);
    float4 gv = ((const float4*)gamma)[tid];
    float4 bv = ((const float4*)beta)[tid];
    bf16x4 o = { (bf16_t)((v.x - mean) * rstd * gv.x + bv.x),
                 (bf16_t)((v.y - mean) * rstd * gv.y + bv.y),
                 (bf16_t)((v.z - mean) * rstd * gv.z + bv.z),
                 (bf16_t)((v.w - mean) * rstd * gv.w + bv.w) };
    *(bf16x4*)(xout + (size_t)row * 1024 + tid * 4) = o;
  }
}

// ---------------- NT GEMM: C[M,N] = A[M,K] * Bw[N,K]^T + bias --------------
__global__ __launch_bounds__(256) void gemm_bt(
    const bf16_t* __restrict__ A, const bf16_t* __restrict__ Bw,
    const float* __restrict__ b0, const float* __restrict__ b1,
    const float* __restrict__ b2,
    void* __restrict__ o0, void* __restrict__ o1, void* __restrict__ o2,
    int M, int N, int K, int fused)
{
  __shared__ __align__(16) bf16_t a_lds[2][128][32];
  __shared__ __align__(16) bf16_t b_lds[2][128][32];
  const int tid = threadIdx.x;
  const int l = tid & 63, w = tid >> 6;
  const int wr = w >> 1, wc = w & 1;
  const int m0 = blockIdx.y * 128, n0 = blockIdx.x * 128;
  const int lr = l & 15, lg = l >> 4;

  f32x4 acc[4][4] = {};

  const int srow = tid >> 2;
  const int scol = (tid & 3) * 8;
  const bf16_t* ag = A  + (size_t)(m0 + srow) * K + scol;
  const bf16_t* bg = Bw + (size_t)(n0 + srow) * K + scol;

  gload16((char*)a_lds[0] + tid * 16,        ag);
  gload16((char*)a_lds[0] + 4096 + tid * 16, ag + (size_t)64 * K);
  gload16((char*)b_lds[0] + tid * 16,        bg);
  gload16((char*)b_lds[0] + 4096 + tid * 16, bg + (size_t)64 * K);
  __syncthreads();

  int cur = 0;
  for (int k0 = 0; k0 < K; k0 += 32) {
    if (k0 + 32 < K) {
      gload16((char*)a_lds[cur ^ 1] + tid * 16,        ag + k0 + 32);
      gload16((char*)a_lds[cur ^ 1] + 4096 + tid * 16, ag + (size_t)64 * K + k0 + 32);
      gload16((char*)b_lds[cur ^ 1] + tid * 16,        bg + k0 + 32);
      gload16((char*)b_lds[cur ^ 1] + 4096 + tid * 16, bg + (size_t)64 * K + k0 + 32);
    }
    bf16x8 af[4], bf[4];
#pragma unroll
    for (int i = 0; i < 4; ++i) {
      af[i] = *(const bf16x8*)&a_lds[cur][wr * 64 + i * 16 + lr][lg * 8];
      bf[i] = *(const bf16x8*)&b_lds[cur][wc * 64 + i * 16 + lr][lg * 8];
    }
#pragma unroll
    for (int i = 0; i < 4; ++i)
#pragma unroll
      for (int j = 0; j < 4; ++j)
        acc[i][j] = MFMA16(af[i], bf[j], acc[i][j]);
    __syncthreads();
    cur ^= 1;
  }

  int matsel = fused ? (n0 >> 10) : 0;
  const float* bias = matsel == 0 ? b0 : matsel == 1 ? b1 : b2;
  float bs[4];
#pragma unroll
  for (int j = 0; j < 4; ++j) bs[j] = bias[(n0 + wc * 64 + j * 16 + lr) & 1023];

#pragma unroll
  for (int i = 0; i < 4; ++i) {
#pragma unroll
    for (int j = 0; j < 4; ++j) {
      if (fused && matsel == 2) {
        // V^T scatter: rows r are consecutive s -> one packed bf16x4 store
        int row0 = m0 + wr * 64 + i * 16 + lg * 4;
        int col  = n0 + wc * 64 + j * 16 + lr;
        int nn = col & 1023;
        int bb = row0 >> 11, s0 = row0 & 2047, hh = nn >> 6, d = nn & 63;
        bf16x4 pv;
#pragma unroll
        for (int r = 0; r < 4; ++r) pv[r] = (bf16_t)(acc[i][j][r] + bs[j]);
        *(bf16x4*)((bf16_t*)o2 + ((((size_t)bb * 16 + hh) * 64) + d) * 2048 + s0) = pv;
      } else {
#pragma unroll
        for (int r = 0; r < 4; ++r) {
          int row = m0 + wr * 64 + i * 16 + lg * 4 + r;
          int col = n0 + wc * 64 + j * 16 + lr;
          float v = acc[i][j][r] + bs[j];
          if (!fused) {
            ((float*)o0)[(size_t)row * N + col] = v;
          } else {
            int nn = col & 1023;
            int bb = row >> 11, s = row & 2047, hh = nn >> 6, d = nn & 63;
            bf16_t* o = matsel ? (bf16_t*)o1 : (bf16_t*)o0;
            // fold 1/sqrt(hd) * log2(e) into q -> scores arrive in log2 domain
            if (matsel == 0) v *= 0.18033688011112042f;
            o[((((size_t)bb * 16 + hh) * 2048 + s) << 6) + d] = (bf16_t)v;
          }
        }
      }
    }
  }
}

// ---------------- fused attention (32x32 MFMA, in-register P) --------------
// flat grid 512 (XCD-swizzled), 512 thr = 8 waves x 32 q-rows = 256 q-rows.
// 4-deep LDS ring (64 KB, 2 blocks/CU = 16 waves/CU), prefetch 2 tiles ahead,
// raw s_barrier + counted vmcnt(4) (no full drain in main loop).
// One tile: {issue t+2 stage; vmcnt(4) [own t landed]; barrier [block-wide];
// compute t}. Tail peels vmcnt(2)/vmcnt(0).
#define ATTN_TILE(T_, ISSUE_, VM_)                                            \
  {                                                                           \
    if (ISSUE_) {                                                             \
      gload16((char*)k_lds[((T_) + 2) & 3] + tid * 16,                        \
              kbase + koff + ((T_) + 2) * 8192);                              \
      gload16((char*)v_lds[((T_) + 2) & 3] + tid * 16,                        \
              vbase + voff + ((T_) + 2) * 128);                               \
    }                                                                         \
    asm volatile("s_waitcnt vmcnt(" #VM_ ")" ::: "memory");                   \
    __builtin_amdgcn_s_barrier();                                             \
    __builtin_amdgcn_sched_barrier(0);                                        \
    const char* kldsb_ = (const char*)k_lds[(T_) & 3];                        \
    const char* vldsb_ = (const char*)v_lds[(T_) & 3];                        \
    _Pragma("unroll")                                                         \
    for (int kh = 0; kh < 2; ++kh) {                                          \
      f32x16 sc = {};                                                         \
      __builtin_amdgcn_s_setprio(1);                                          \
      _Pragma("unroll")                                                       \
      for (int ch = 0; ch < 4; ++ch) {                                        \
        bf16x8 kf = *(const bf16x8*)(kldsb_ + (kh * 32 + l31) * 128           \
                                     + ((ch * 32 + hi * 16) ^ swzr));         \
        sc = MFMA32(kf, qf[ch], sc);                                          \
      }                                                                       \
      __builtin_amdgcn_s_setprio(0);                                          \
      unsigned U[8];                                                          \
      _Pragma("unroll")                                                       \
      for (int m = 0; m < 8; ++m) {                                           \
        float t0 = VEXP2(-sc[2 * m]);                                         \
        float t1 = VEXP2(-sc[2 * m + 1]);                                     \
        float d0 = fmaf(emu * t0, t0, t0);                                    \
        float d1 = fmaf(emu * t1, t1, t1);                                    \
        float inv = __builtin_amdgcn_rcpf(d0 * d1);                           \
        float w0 = inv * d1;                                                  \
        float w1 = inv * d0;                                                  \
        rs0 += w0; rs1 += w1;                                                 \
        U[m] = cvtpk_bf16(w0, w1);                                            \
      }                                                                       \
      plane32_swap(U[0], U[2]);                                               \
      plane32_swap(U[1], U[3]);                                               \
      plane32_swap(U[4], U[6]);                                               \
      plane32_swap(U[5], U[7]);                                               \
      __builtin_amdgcn_s_setprio(1);                                          \
      _Pragma("unroll")                                                       \
      for (int cc = 0; cc < 2; ++cc) {                                        \
        u32x4 uu = { U[cc * 4 + 0], U[cc * 4 + 1], U[cc * 4 + 2],             \
                     U[cc * 4 + 3] };                                         \
        bf16x8 pa = __builtin_bit_cast(bf16x8, uu);                           \
        int kcol = (kh * 2 + cc) * 32 + hi * 16;                              \
        _Pragma("unroll")                                                     \
        for (int df = 0; df < 2; ++df) {                                      \
          bf16x8 vf = *(const bf16x8*)(vldsb_ + (df * 32 + l31) * 128         \
                                       + (kcol ^ swzr));                      \
          oAcc[df] = MFMA32(pa, vf, oAcc[df]);                                \
        }                                                                     \
      }                                                                       \
      __builtin_amdgcn_s_setprio(0);                                          \
    }                                                                         \
  }

__global__ __launch_bounds__(512) void attn_k(
    const bf16_t* __restrict__ q, const bf16_t* __restrict__ k,
    const bf16_t* __restrict__ vT, const float* __restrict__ mu_p,
    bf16_t* __restrict__ out)
{
  const int S = 2048;
  int hw = blockIdx.x;
  int vid = (hw & 7) * 64 + (hw >> 3);    // 8 XCD chunks of 64; 8 blocks/bh
  int qt = vid & 7;                       // q-tile of 256 rows
  int bh = vid >> 3;
  int h = bh & 15, b = bh >> 4;

  const bf16_t* qb = q  + ((size_t)bh * S + qt * 256) * 64;
  const char* kbase = (const char*)(k  + (size_t)bh * S * 64);
  const char* vbase = (const char*)(vT + (size_t)bh * 64 * S);
  const float emu = __expf(mu_p[0]);      // e^mu (natural)

  __shared__ __align__(16) bf16_t k_lds[4][64][64];   // 32 KB ring
  __shared__ __align__(16) bf16_t v_lds[4][64][64];   // 32 KB ring

  const int tid = threadIdx.x, l = tid & 63, w = tid >> 6;  // w in 0..7
  const int l31 = l & 31, hi = l >> 5;
  const int swzr = (l31 & 7) << 4;        // row&7 XOR slot (row = *32k + l31)

  // Q fragments: lane holds Q[q=w*32+l31][hd=16ch+8hi+j]
  bf16x8 qf[4];
#pragma unroll
  for (int ch = 0; ch < 4; ++ch)
    qf[ch] = *(const bf16x8*)(qb + (size_t)(w * 32 + l31) * 64 + ch * 16 + hi * 8);

  // staging: 512 thr x 16B = 8 KB = one whole K (or V) tile per call
  const int srow = tid >> 3;                        // 0..63
  const int ssw  = ((tid & 7) * 16) ^ ((srow & 7) << 4);
  const int koff = srow * 128 + ssw;                // +t*8192
  const int voff = srow * 4096 + ssw;               // +t*128

  f32x16 oAcc[2] = {};                    // [dfrag]
  float rs0 = 0.f, rs1 = 0.f;

  // prologue: stage tiles 0 and 1 (2 calls each; issue order defines vmcnt)
  gload16((char*)k_lds[0] + tid * 16, kbase + koff);
  gload16((char*)v_lds[0] + tid * 16, vbase + voff);
  gload16((char*)k_lds[1] + tid * 16, kbase + koff + 8192);
  gload16((char*)v_lds[1] + tid * 16, vbase + voff + 128);

#pragma unroll 4
  for (int t = 0; t < 28; ++t) ATTN_TILE(t, true, 4);
  ATTN_TILE(28, true, 4);
  ATTN_TILE(29, true, 4);
  ATTN_TILE(30, false, 2);
  ATTN_TILE(31, false, 0);

  // row sums: lane holds partial for q = l31; lanes l and l+32 complete the row
  float rs = rs0 + rs1;
  rs += __shfl_xor(rs, 32);
  float rinv = __builtin_amdgcn_rcpf(rs);

#pragma unroll
  for (int r = 0; r < 16; ++r) {
    int q_loc = (r & 3) + 8 * (r >> 2) + 4 * hi;
    float ro = __shfl(rinv, q_loc);
    size_t row = (size_t)b * 2048 + qt * 256 + w * 32 + q_loc;
#pragma unroll
    for (int df = 0; df < 2; ++df) {
      out[row * 1024 + h * 64 + df * 32 + l31] = (bf16_t)(oAcc[df][r] * ro);
    }
  }
}

// ---------------------------------------------------------------------------
extern "C" void kernel_launch(void* const* d_in, const int* in_sizes, int n_in,
                              void* d_out, int out_size, void* d_ws, size_t ws_size,
                              hipStream_t stream) {
  const float* seq = (const float*)d_in[0];
  const float* g   = (const float*)d_in[1];
  const float* be  = (const float*)d_in[2];
  const float* Wq  = (const float*)d_in[3];
  const float* bq  = (const float*)d_in[4];
  const float* Wk  = (const float*)d_in[5];
  const float* bk  = (const float*)d_in[6];
  const float* Wv  = (const float*)d_in[7];
  const float* bv  = (const float*)d_in[8];
  const float* Wo  = (const float*)d_in[9];
  const float* bo  = (const float*)d_in[10];
  const float* mu  = (const float*)d_in[11];

  char* ws = (char*)d_ws;
  bf16_t* xb   = (bf16_t*)ws;  ws += (size_t)8192 * 1024 * 2;
  bf16_t* wAll = (bf16_t*)ws;  ws += (size_t)4 * 1024 * 1024 * 2;
  bf16_t* qb   = (bf16_t*)ws;  ws += (size_t)8192 * 1024 * 2;
  bf16_t* kbuf = (bf16_t*)ws;  ws += (size_t)8192 * 1024 * 2;
  bf16_t* vtb  = (bf16_t*)ws;  ws += (size_t)8192 * 1024 * 2;
  bf16_t* ab   = (bf16_t*)ws;  ws += (size_t)8192 * 1024 * 2;
  bf16_t* wqkv = wAll;
  bf16_t* wob  = wAll + (size_t)3 * 1024 * 1024;

  dim3 blk(256);
  prep_k<<<dim3(12288), blk, 0, stream>>>(Wq, Wk, Wv, Wo, wAll, seq, g, be, xb);
  gemm_bt<<<dim3(24, 64), blk, 0, stream>>>(xb, wqkv, bq, bk, bv,
                                            qb, kbuf, vtb, 8192, 3072, 1024, 1);
  attn_k<<<dim3(512), dim3(512), 0, stream>>>(qb, kbuf, vtb, mu, ab);
  gemm_bt<<<dim3(8, 64), blk, 0, stream>>>(ab, wob, bo, nullptr, nullptr,
                                           d_out, nullptr, nullptr, 8192, 1024, 1024, 0);
}

// Round 16
// 195.614 us; speedup vs baseline: 1.9818x; 1.0596x over previous
//
#include <hip/hip_runtime.h>
#include <hip/hip_bf16.h>
#include <cstdint>
#include <cstddef>

// ---------------------------------------------------------------------------
// Attention block on MI355X (gfx950), bf16 MFMA everywhere.
//   x = LN(seq); q,k,v = x@W{q,k,v}.T + b (q pre-scaled by 0.125*log2e)
//   s' = q.k (log2 domain); e = 2^s'; w = e^2/(e+e^mu) = rcp(t + emu*t^2)
//   P = w / rowsum(w); out = (P @ v, heads merged) @ Wo.T + bo
// GEMMs: 256x128 tile, BK=64, 8 waves (4Mx2N), dbuf LDS + XOR swizzle,
// 2-phase/K-tile schedule with counted vmcnt (never 0 in loop), setprio.
// Attn: r15-verified (107.5 us) — unchanged.
// ---------------------------------------------------------------------------

typedef __bf16 bf16_t;
typedef __bf16 bf16x4 __attribute__((ext_vector_type(4)));
typedef __bf16 bf16x8 __attribute__((ext_vector_type(8)));
typedef float  f32x4  __attribute__((ext_vector_type(4)));
typedef float  f32x16 __attribute__((ext_vector_type(16)));
typedef unsigned u32x4 __attribute__((ext_vector_type(4)));

#define MFMA16(a, b, c) __builtin_amdgcn_mfma_f32_16x16x32_bf16((a), (b), (c), 0, 0, 0)
#define MFMA32(a, b, c) __builtin_amdgcn_mfma_f32_32x32x16_bf16((a), (b), (c), 0, 0, 0)

#if __has_builtin(__builtin_amdgcn_exp2f)
#define VEXP2(x) __builtin_amdgcn_exp2f(x)
#else
#define VEXP2(x) __expf((x) * 0.6931471805599453f)
#endif

__device__ __forceinline__ unsigned cvtpk_bf16(float a, float b) {
  unsigned r;
  asm("v_cvt_pk_bf16_f32 %0, %1, %2" : "=v"(r) : "v"(a), "v"(b));
  return r;
}

__device__ __forceinline__ void plane32_swap(unsigned& a, unsigned& b) {
  asm volatile("v_permlane32_swap_b32 %0, %1" : "+v"(a), "+v"(b));
}

__device__ __forceinline__ void gload16(void* lds, const void* g) {
  __builtin_amdgcn_global_load_lds(
      (__attribute__((address_space(1))) void*)(uintptr_t)g,
      (__attribute__((address_space(3))) void*)(uint32_t)(uintptr_t)lds,
      16, 0, 0);
}

// ---------------- fused prep: weights fp32->bf16  +  LayerNorm -------------
__global__ __launch_bounds__(256) void prep_k(
    const float* __restrict__ s0, const float* __restrict__ s1,
    const float* __restrict__ s2, const float* __restrict__ s3,
    bf16_t* __restrict__ wdst,
    const float* __restrict__ x, const float* __restrict__ gamma,
    const float* __restrict__ beta, bf16_t* __restrict__ xout)
{
  int bid = blockIdx.x;
  int tid = threadIdx.x;
  if (bid < 4096) {
    int part = bid >> 10;
    const float* src = part == 0 ? s0 : part == 1 ? s1 : part == 2 ? s2 : s3;
    int i = (bid & 1023) * 256 + tid;
    float4 v = ((const float4*)src)[i];
    bf16x4 o = { (bf16_t)v.x, (bf16_t)v.y, (bf16_t)v.z, (bf16_t)v.w };
    *(bf16x4*)(wdst + (((size_t)part) << 20) + (size_t)i * 4) = o;
  } else {
    int row = bid - 4096;
    float4 v = ((const float4*)(x + (size_t)row * 1024))[tid];
    float s  = v.x + v.y + v.z + v.w;
    float ss = v.x * v.x + v.y * v.y + v.z * v.z + v.w * v.w;
#pragma unroll
    for (int m = 1; m < 64; m <<= 1) { s += __shfl_xor(s, m); ss += __shfl_xor(ss, m); }
    __shared__ float sh_s[4], sh_q[4];
    int w = tid >> 6;
    if ((tid & 63) == 0) { sh_s[w] = s; sh_q[w] = ss; }
    __syncthreads();
    s  = sh_s[0] + sh_s[1] + sh_s[2] + sh_s[3];
    ss = sh_q[0] + sh_q[1] + sh_q[2] + sh_q[3];
    float mean = s * (1.0f / 1024.0f);
    float var  = ss * (1.0f / 1024.0f) - mean * mean;
    float rstd = rsqrtf(var + 1e-6f);
    float4 gv = ((const float4*)gamma)[tid];
    float4 bv = ((const float4*)beta)[tid];
    bf16x4 o = { (bf16_t)((v.x - mean) * rstd * gv.x + bv.x),
                 (bf16_t)((v.y - mean) * rstd * gv.y + bv.y),
                 (bf16_t)((v.z - mean) * rstd * gv.z + bv.z),
                 (bf16_t)((v.w - mean) * rstd * gv.w + bv.w) };
    *(bf16x4*)(xout + (size_t)row * 1024 + tid * 4) = o;
  }
}

// ---------------- 256x128 NT GEMM, BK=64, 2-phase counted-vmcnt schedule ----
// C[M,N] = A[M,1024] * Bw[N,1024]^T + bias.  8 waves as 4M x 2N; per-wave
// 64x64 out (acc 4x4).  LDS 96 KB: a[2][256][64], b[2][128][64], XOR-swizzled
// (linear gload dest + pre-swizzled source + swizzled ds_read — r2-verified).
// Per K-tile (64): 2 phases; phase p: {issue 3 gloads for tile t+1;
// [p0: vmcnt(3)]; barrier; sched_barrier; ds_read frags; 16 MFMA; barrier}.
// vmcnt proof: 6 loads/tile, +3 just issued; oldest 6 = tile t -> wait(3).
#define G_PHASE(T_, P_, ISSUE_, VM_, DOVM_)                                   \
  {                                                                           \
    if (ISSUE_) {                                                             \
      const char* asrc_ = ag + ((T_) + 1) * 128;                              \
      const char* bsrc_ = bg + ((T_) + 1) * 128;                              \
      char* adst_ = (char*)a_lds[((T_) + 1) & 1] + tid * 16;                  \
      char* bdst_ = (char*)b_lds[((T_) + 1) & 1] + tid * 16;                  \
      if ((P_) == 0) {                                                        \
        gload16(adst_,         asrc_);                                        \
        gload16(adst_ + 8192,  asrc_ + 131072);                               \
        gload16(bdst_,         bsrc_);                                        \
      } else {                                                                \
        gload16(adst_ + 16384, asrc_ + 262144);                               \
        gload16(adst_ + 24576, asrc_ + 393216);                               \
        gload16(bdst_ + 8192,  bsrc_ + 131072);                               \
      }                                                                       \
    }                                                                         \
    if (DOVM_) { asm volatile("s_waitcnt vmcnt(" VM_ ")" ::: "memory"); }     \
    __builtin_amdgcn_s_barrier();                                             \
    __builtin_amdgcn_sched_barrier(0);                                        \
    const char* al_ = (const char*)a_lds[(T_) & 1];                           \
    const char* bl_ = (const char*)b_lds[(T_) & 1];                           \
    if ((P_) == 0) {                                                          \
      _Pragma("unroll")                                                       \
      for (int j = 0; j < 4; ++j)                                             \
        _Pragma("unroll")                                                     \
        for (int ks = 0; ks < 2; ++ks)                                        \
          bf[j][ks] = *(const bf16x8*)(bl_ + (wn * 64 + j * 16 + lr) * 128    \
                          + ((ks * 64 + lg * 16) ^ swzr));                    \
    }                                                                         \
    _Pragma("unroll")                                                         \
    for (int ri = 0; ri < 2; ++ri) {                                          \
      const int i_ = (P_) * 2 + ri;                                           \
      bf16x8 af0 = *(const bf16x8*)(al_ + (wm * 64 + i_ * 16 + lr) * 128      \
                        + ((lg * 16) ^ swzr));                                \
      bf16x8 af1 = *(const bf16x8*)(al_ + (wm * 64 + i_ * 16 + lr) * 128      \
                        + ((64 + lg * 16) ^ swzr));                           \
      __builtin_amdgcn_s_setprio(1);                                          \
      _Pragma("unroll")                                                       \
      for (int j = 0; j < 4; ++j) {                                           \
        acc[i_][j] = MFMA16(af0, bf[j][0], acc[i_][j]);                       \
        acc[i_][j] = MFMA16(af1, bf[j][1], acc[i_][j]);                       \
      }                                                                       \
      __builtin_amdgcn_s_setprio(0);                                          \
    }                                                                         \
    __builtin_amdgcn_s_barrier();                                             \
  }

#define G_TILE(T_, ISSUE_, VM0_)     \
  G_PHASE(T_, 0, ISSUE_, VM0_, true) \
  G_PHASE(T_, 1, ISSUE_, "0", false)

__global__ __launch_bounds__(512) void gemm256(
    const bf16_t* __restrict__ A, const bf16_t* __restrict__ Bw,
    const float* __restrict__ b0, const float* __restrict__ b1,
    const float* __restrict__ b2,
    void* __restrict__ o0, void* __restrict__ o1, void* __restrict__ o2,
    int nbx, int N, int fused)
{
  __shared__ __align__(16) bf16_t a_lds[2][256][64];   // 64 KB
  __shared__ __align__(16) bf16_t b_lds[2][128][64];   // 32 KB
  const int tid = threadIdx.x, l = tid & 63, wid = tid >> 6;
  const int wm = wid >> 1, wn = wid & 1;
  const int lr = l & 15, lg = l >> 4;
  const int swzr = (lr & 7) << 4;

  int hw = blockIdx.x;
  int cpx = (nbx * 32) >> 3;
  int vid = (hw & 7) * cpx + (hw >> 3);
  int by = vid / nbx, bx = vid % nbx;
  const int m0 = by * 256, n0 = bx * 128;

  f32x4 acc[4][4] = {};

  // staging geometry: lane stages 16B; row = chunk*64 + tid>>3, semantic col
  // pre-swizzled so linear LDS dest holds swizzled layout (involution).
  const int srow = tid >> 3;
  const int ssw  = ((tid & 7) * 16) ^ ((srow & 7) << 4);
  const char* ag = (const char*)A  + (size_t)(m0 + srow) * 2048 + ssw;
  const char* bg = (const char*)Bw + (size_t)(n0 + srow) * 2048 + ssw;

  // prologue: stage K-tile 0 (A chunks 0-3, B chunks 0-1)
  gload16((char*)a_lds[0] + tid * 16,         ag);
  gload16((char*)a_lds[0] + 8192 + tid * 16,  ag + 131072);
  gload16((char*)a_lds[0] + 16384 + tid * 16, ag + 262144);
  gload16((char*)a_lds[0] + 24576 + tid * 16, ag + 393216);
  gload16((char*)b_lds[0] + tid * 16,         bg);
  gload16((char*)b_lds[0] + 8192 + tid * 16,  bg + 131072);

#pragma unroll 2
  for (int t = 0; t < 15; ++t) {
    bf16x8 bf[4][2];
    G_TILE(t, true, "3");
  }
  {
    bf16x8 bf[4][2];
    G_TILE(15, false, "0");
  }

  int matsel = fused ? (n0 >> 10) : 0;
  const float* bias = matsel == 0 ? b0 : matsel == 1 ? b1 : b2;
  float bs[4];
#pragma unroll
  for (int j = 0; j < 4; ++j) bs[j] = bias[(n0 + wn * 64 + j * 16 + lr) & 1023];

#pragma unroll
  for (int i = 0; i < 4; ++i) {
#pragma unroll
    for (int j = 0; j < 4; ++j) {
      if (fused && matsel == 2) {
        int row0 = m0 + wm * 64 + i * 16 + lg * 4;
        int col  = n0 + wn * 64 + j * 16 + lr;
        int nn = col & 1023;
        int bb = row0 >> 11, s0 = row0 & 2047, hh = nn >> 6, d = nn & 63;
        bf16x4 pv;
#pragma unroll
        for (int r = 0; r < 4; ++r) pv[r] = (bf16_t)(acc[i][j][r] + bs[j]);
        *(bf16x4*)((bf16_t*)o2 + ((((size_t)bb * 16 + hh) * 64) + d) * 2048 + s0) = pv;
      } else {
#pragma unroll
        for (int r = 0; r < 4; ++r) {
          int row = m0 + wm * 64 + i * 16 + lg * 4 + r;
          int col = n0 + wn * 64 + j * 16 + lr;
          float v = acc[i][j][r] + bs[j];
          if (!fused) {
            ((float*)o0)[(size_t)row * N + col] = v;
          } else {
            int nn = col & 1023;
            int bb = row >> 11, s = row & 2047, hh = nn >> 6, d = nn & 63;
            bf16_t* o = matsel ? (bf16_t*)o1 : (bf16_t*)o0;
            if (matsel == 0) v *= 0.18033688011112042f;  // 1/8 * log2(e)
            o[((((size_t)bb * 16 + hh) * 2048 + s) << 6) + d] = (bf16_t)v;
          }
        }
      }
    }
  }
}

// ---------------- fused attention (r15-verified, 107.5 us) -----------------
#define ATTN_TILE(T_, ISSUE_, VM_)                                            \
  {                                                                           \
    if (ISSUE_) {                                                             \
      gload16((char*)k_lds[((T_) + 2) & 3] + tid * 16,                        \
              kbase + koff + ((T_) + 2) * 8192);                              \
      gload16((char*)v_lds[((T_) + 2) & 3] + tid * 16,                        \
              vbase + voff + ((T_) + 2) * 128);                               \
    }                                                                         \
    asm volatile("s_waitcnt vmcnt(" #VM_ ")" ::: "memory");                   \
    __builtin_amdgcn_s_barrier();                                             \
    __builtin_amdgcn_sched_barrier(0);                                        \
    const char* kldsb_ = (const char*)k_lds[(T_) & 3];                        \
    const char* vldsb_ = (const char*)v_lds[(T_) & 3];                        \
    _Pragma("unroll")                                                         \
    for (int kh = 0; kh < 2; ++kh) {                                          \
      f32x16 sc = {};                                                         \
      __builtin_amdgcn_s_setprio(1);                                          \
      _Pragma("unroll")                                                       \
      for (int ch = 0; ch < 4; ++ch) {                                        \
        bf16x8 kf = *(const bf16x8*)(kldsb_ + (kh * 32 + l31) * 128           \
                                     + ((ch * 32 + hi * 16) ^ swzr));         \
        sc = MFMA32(kf, qf[ch], sc);                                          \
      }                                                                       \
      __builtin_amdgcn_s_setprio(0);                                          \
      unsigned U[8];                                                          \
      _Pragma("unroll")                                                       \
      for (int m = 0; m < 8; ++m) {                                           \
        float t0 = VEXP2(-sc[2 * m]);                                         \
        float t1 = VEXP2(-sc[2 * m + 1]);                                     \
        float d0 = fmaf(emu * t0, t0, t0);                                    \
        float d1 = fmaf(emu * t1, t1, t1);                                    \
        float inv = __builtin_amdgcn_rcpf(d0 * d1);                           \
        float w0 = inv * d1;                                                  \
        float w1 = inv * d0;                                                  \
        rs0 += w0; rs1 += w1;                                                 \
        U[m] = cvtpk_bf16(w0, w1);                                            \
      }                                                                       \
      plane32_swap(U[0], U[2]);                                               \
      plane32_swap(U[1], U[3]);                                               \
      plane32_swap(U[4], U[6]);                                               \
      plane32_swap(U[5], U[7]);                                               \
      __builtin_amdgcn_s_setprio(1);                                          \
      _Pragma("unroll")                                                       \
      for (int cc = 0; cc < 2; ++cc) {                                        \
        u32x4 uu = { U[cc * 4 + 0], U[cc * 4 + 1], U[cc * 4 + 2],             \
                     U[cc * 4 + 3] };                                         \
        bf16x8 pa = __builtin_bit_cast(bf16x8, uu);                           \
        int kcol = (kh * 2 + cc) * 32 + hi * 16;                              \
        _Pragma("unroll")                                                     \
        for (int df = 0; df < 2; ++df) {                                      \
          bf16x8 vf = *(const bf16x8*)(vldsb_ + (df * 32 + l31) * 128         \
                                       + (kcol ^ swzr));                      \
          oAcc[df] = MFMA32(pa, vf, oAcc[df]);                                \
        }                                                                     \
      }                                                                       \
      __builtin_amdgcn_s_setprio(0);                                          \
    }                                                                         \
  }

__global__ __launch_bounds__(512) void attn_k(
    const bf16_t* __restrict__ q, const bf16_t* __restrict__ k,
    const bf16_t* __restrict__ vT, const float* __restrict__ mu_p,
    bf16_t* __restrict__ out)
{
  const int S = 2048;
  int hw = blockIdx.x;
  int vid = (hw & 7) * 64 + (hw >> 3);
  int qt = vid & 7;
  int bh = vid >> 3;
  int h = bh & 15, b = bh >> 4;

  const bf16_t* qb = q  + ((size_t)bh * S + qt * 256) * 64;
  const char* kbase = (const char*)(k  + (size_t)bh * S * 64);
  const char* vbase = (const char*)(vT + (size_t)bh * 64 * S);
  const float emu = __expf(mu_p[0]);

  __shared__ __align__(16) bf16_t k_lds[4][64][64];
  __shared__ __align__(16) bf16_t v_lds[4][64][64];

  const int tid = threadIdx.x, l = tid & 63, w = tid >> 6;
  const int l31 = l & 31, hi = l >> 5;
  const int swzr = (l31 & 7) << 4;

  bf16x8 qf[4];
#pragma unroll
  for (int ch = 0; ch < 4; ++ch)
    qf[ch] = *(const bf16x8*)(qb + (size_t)(w * 32 + l31) * 64 + ch * 16 + hi * 8);

  const int srow = tid >> 3;
  const int ssw  = ((tid & 7) * 16) ^ ((srow & 7) << 4);
  const int koff = srow * 128 + ssw;
  const int voff = srow * 4096 + ssw;

  f32x16 oAcc[2] = {};
  float rs0 = 0.f, rs1 = 0.f;

  gload16((char*)k_lds[0] + tid * 16, kbase + koff);
  gload16((char*)v_lds[0] + tid * 16, vbase + voff);
  gload16((char*)k_lds[1] + tid * 16, kbase + koff + 8192);
  gload16((char*)v_lds[1] + tid * 16, vbase + voff + 128);

#pragma unroll 4
  for (int t = 0; t < 28; ++t) ATTN_TILE(t, true, 4);
  ATTN_TILE(28, true, 4);
  ATTN_TILE(29, true, 4);
  ATTN_TILE(30, false, 2);
  ATTN_TILE(31, false, 0);

  float rs = rs0 + rs1;
  rs += __shfl_xor(rs, 32);
  float rinv = __builtin_amdgcn_rcpf(rs);

#pragma unroll
  for (int r = 0; r < 16; ++r) {
    int q_loc = (r & 3) + 8 * (r >> 2) + 4 * hi;
    float ro = __shfl(rinv, q_loc);
    size_t row = (size_t)b * 2048 + qt * 256 + w * 32 + q_loc;
#pragma unroll
    for (int df = 0; df < 2; ++df) {
      out[row * 1024 + h * 64 + df * 32 + l31] = (bf16_t)(oAcc[df][r] * ro);
    }
  }
}

// ---------------------------------------------------------------------------
extern "C" void kernel_launch(void* const* d_in, const int* in_sizes, int n_in,
                              void* d_out, int out_size, void* d_ws, size_t ws_size,
                              hipStream_t stream) {
  const float* seq = (const float*)d_in[0];
  const float* g   = (const float*)d_in[1];
  const float* be  = (const float*)d_in[2];
  const float* Wq  = (const float*)d_in[3];
  const float* bq  = (const float*)d_in[4];
  const float* Wk  = (const float*)d_in[5];
  const float* bk  = (const float*)d_in[6];
  const float* Wv  = (const float*)d_in[7];
  const float* bv  = (const float*)d_in[8];
  const float* Wo  = (const float*)d_in[9];
  const float* bo  = (const float*)d_in[10];
  const float* mu  = (const float*)d_in[11];

  char* ws = (char*)d_ws;
  bf16_t* xb   = (bf16_t*)ws;  ws += (size_t)8192 * 1024 * 2;
  bf16_t* wAll = (bf16_t*)ws;  ws += (size_t)4 * 1024 * 1024 * 2;
  bf16_t* qb   = (bf16_t*)ws;  ws += (size_t)8192 * 1024 * 2;
  bf16_t* kbuf = (bf16_t*)ws;  ws += (size_t)8192 * 1024 * 2;
  bf16_t* vtb  = (bf16_t*)ws;  ws += (size_t)8192 * 1024 * 2;
  bf16_t* ab   = (bf16_t*)ws;  ws += (size_t)8192 * 1024 * 2;
  bf16_t* wqkv = wAll;
  bf16_t* wob  = wAll + (size_t)3 * 1024 * 1024;

  prep_k<<<dim3(12288), dim3(256), 0, stream>>>(Wq, Wk, Wv, Wo, wAll, seq, g, be, xb);
  gemm256<<<dim3(768), dim3(512), 0, stream>>>(xb, wqkv, bq, bk, bv,
                                               qb, kbuf, vtb, 24, 3072, 1);
  attn_k<<<dim3(512), dim3(512), 0, stream>>>(qb, kbuf, vtb, mu, ab);
  gemm256<<<dim3(256), dim3(512), 0, stream>>>(ab, wob, bo, nullptr, nullptr,
                                               d_out, nullptr, nullptr, 8, 1024, 0);
}